// Round 8
// baseline (1036.278 us; speedup 1.0000x reference)
//
#include <hip/hip_runtime.h>

#define BB 64
#define CC 128
#define CO 128
#define TTOT 256
#define VV 25
#define SS 3
#define RR 16
#define GG 32
#define EPSV 1e-5f

typedef __attribute__((ext_vector_type(8))) __bf16 bf16x8;
typedef __attribute__((ext_vector_type(4))) float f32x4;

static __device__ __forceinline__ ushort f2bf(float f) {      // RNE
    unsigned u = __float_as_uint(f);
    u = (u + 0x7FFF + ((u >> 16) & 1)) >> 16;
    return (ushort)u;
}
static __device__ __forceinline__ ushort f2bf_fast(float f) { // round-half-up
    return (ushort)((__float_as_uint(f) + 0x8000u) >> 16);
}
static __device__ __forceinline__ float bf2f(ushort h) {
    return __uint_as_float(((unsigned)h) << 16);
}
static __device__ __forceinline__ f32x4 mfma16(bf16x8 a, bf16x8 b, f32x4 c) {
    return __builtin_amdgcn_mfma_f32_16x16x32_bf16(a, b, c, 0, 0, 0);
}
// raw barrier: LDS-visibility only; global prefetches stay in flight (m201 pattern)
static __device__ __forceinline__ void bar_lds() {
    asm volatile("s_waitcnt lgkmcnt(0)" ::: "memory");
    __builtin_amdgcn_s_barrier();
}

// ---------------- K0: x -> xg (bf16 frag layout, k padded to 32 w/ zeros) + xm ----------------
// xg: [b][c8(16)][n' = t*32+k (8192)][cc(8)] bf16
__global__ __launch_bounds__(512) void k_xpose(const float* __restrict__ x,
                                               ushort* __restrict__ xg,
                                               float* __restrict__ xm) {
    int bid = blockIdx.x;                  // b*16 + c8
    int b = bid >> 4, c8 = bid & 15;
    int tid = threadIdx.x;
    __shared__ float sx[8 * 800];
    float xsum = 0.f;
    const float* xb = x + ((size_t)b * CC + c8 * 8) * (TTOT * VV);
    ushort* xo = xg + (size_t)bid * 8192 * 8;
    int cc = tid / VV, vv = tid % VV;      // for tid<200
    for (int ti = 0; ti < 8; ++ti) {       // t-chunks of 32
        for (int i = tid; i < 1600; i += 512) {
            int c = i / 200, q = i % 200;
            *(float4*)&sx[c * 800 + q * 4] =
                *(const float4*)&xb[(size_t)c * (TTOT * VV) + ti * 800 + q * 4];
        }
        __syncthreads();
        for (int i = tid; i < 1024; i += 512) {
            int t = i >> 5, k = i & 31;
            union { ushort us[8]; int4 v4; } u;
            if (k < VV) {
#pragma unroll
                for (int c = 0; c < 8; ++c) u.us[c] = f2bf(sx[c * 800 + t * VV + k]);
            } else u.v4 = int4{0, 0, 0, 0};
            *(int4*)&xo[(size_t)((ti * 32 + t) * 32 + k) * 8] = u.v4;
        }
        if (tid < 200) {
#pragma unroll
            for (int t = 0; t < 32; ++t) xsum += sx[cc * 800 + t * VV + vv];
        }
        __syncthreads();
    }
    if (tid < 200) xm[((size_t)b * CC + c8 * 8 + cc) * VV + vv] = xsum * (1.0f / TTOT);
}

// ---------------- K1b: pack Wv into bf16 MFMA fragment order ----------------
__global__ __launch_bounds__(512) void k_pack_wv(const float* __restrict__ Wv,
                                                 ushort* __restrict__ wvp) {
    int t = blockIdx.x * 512 + threadIdx.x;      // < 6144
    int lane = t & 63;
    int ks = (t >> 6) & 3;
    int mt = (t >> 8) & 1;
    int ob = (t >> 9) & 3;
    int s  = t >> 11;
    int o  = ob * 32 + mt * 16 + (lane & 15);
    int c0 = (ks * 4 + (lane >> 4)) * 8;
    const float* src = Wv + ((size_t)s * CO + o) * CC + c0;
    float4 a = *(const float4*)src;
    float4 b = *(const float4*)(src + 4);
    union { ushort us[8]; int4 v; } u;
    u.us[0] = f2bf(a.x); u.us[1] = f2bf(a.y); u.us[2] = f2bf(a.z); u.us[3] = f2bf(a.w);
    u.us[4] = f2bf(b.x); u.us[5] = f2bf(b.y); u.us[6] = f2bf(b.z); u.us[7] = f2bf(b.w);
    *(int4*)&wvp[(size_t)t * 8] = u.v;
}

// ---------------- K2a: q,k projections ----------------
__global__ __launch_bounds__(512) void k_qk(const float* __restrict__ xm,
    const float* __restrict__ Wq, const float* __restrict__ bq,
    const float* __restrict__ Wk, const float* __restrict__ bk,
    float* __restrict__ qb, float* __restrict__ kbuf) {
    int bs = blockIdx.x;
    int b = bs / SS, s = bs % SS;
    int tid = threadIdx.x;
    __shared__ float sxm[CC * VV];
    for (int i = tid; i < CC * VV; i += 512) sxm[i] = xm[(size_t)b * CC * VV + i];
    __syncthreads();
    if (tid < RR * VV) {
        int r = tid / VV, u = tid % VV;
        const float* wq = Wq + ((size_t)s * RR + r) * CC;
        const float* wk = Wk + ((size_t)s * RR + r) * CC;
        float aq = bq[s * RR + r], ak = bk[s * RR + r];
        for (int c = 0; c < CC; ++c) { float xv = sxm[c * VV + u]; aq += wq[c] * xv; ak += wk[c] * xv; }
        qb[bs * 400 + tid] = aq;
        kbuf[bs * 400 + tid] = ak;
    }
}

// ---------------- K2b: relc -> packed bf16 B-fragments; slot k=25 carries bv*rowsum ----------------
__global__ __launch_bounds__(256) void k_relcpack(const float* __restrict__ qb,
    const float* __restrict__ kbuf, const float* __restrict__ Wr,
    const float* __restrict__ br, const float* __restrict__ A,
    const float* __restrict__ alpha, const float* __restrict__ bv,
    ushort* __restrict__ rp) {
    int blk = blockIdx.x;
    int oc = blk & 7, bs = blk >> 3;
    int s = bs % SS;
    int tid = threadIdx.x;
    __shared__ float sq[RR * VV], sk[RR * VV];
    __shared__ float srel[RR][VV * VV];
    __shared__ ushort spack[16 * 1024];
    for (int i = tid; i < RR * VV; i += 256) { sq[i] = qb[bs * 400 + i]; sk[i] = kbuf[bs * 400 + i]; }
    __syncthreads();
    for (int i = tid; i < RR * VV * VV; i += 256) {
        int r = i / (VV * VV), uv = i % (VV * VV);
        srel[r][uv] = tanhf(sq[r * VV + uv / VV] - sk[r * VV + uv % VV]);
    }
    __syncthreads();
    float al = alpha[0];
    for (int i = tid; i < 512; i += 256) {
        int ol = i >> 5, u = i & 31;
        int o = oc * 16 + ol;
        ushort* dst = &spack[ol * 1024 + (u >> 4) * 512 + (u & 15) * 8];
        if (u < VV) {
            float acc[VV];
            float base = br[s * CO + o];
#pragma unroll
            for (int k = 0; k < VV; ++k) acc[k] = base;
            const float* wr = Wr + ((size_t)s * CO + o) * RR;
#pragma unroll
            for (int r = 0; r < RR; ++r) {
                float w = wr[r];
                const float* sr = &srel[r][u * VV];
#pragma unroll
                for (int k = 0; k < VV; ++k) acc[k] += w * sr[k];
            }
            const float* Ab = A + (size_t)s * VV * VV + u * VV;
            float vals[VV]; float rsum = 0.f;
#pragma unroll
            for (int k = 0; k < VV; ++k) { vals[k] = acc[k] * al + Ab[k]; rsum += vals[k]; }
            float bvt = bv[s * CO + o] * rsum;     // pairs with s_v slot k=25 == 1.0
#pragma unroll
            for (int kb4 = 0; kb4 < 4; ++kb4) {
                union { ushort us[8]; int4 v; } pk;
#pragma unroll
                for (int j = 0; j < 8; ++j) {
                    int kk = kb4 * 8 + j;
                    pk.us[j] = (kk < VV) ? f2bf(vals[kk])
                             : (kk == VV) ? f2bf(bvt) : (ushort)0;
                }
                *(int4*)&dst[kb4 * 128] = pk.v;
            }
        } else {
#pragma unroll
            for (int kb4 = 0; kb4 < 4; ++kb4)
                *(int4*)&dst[kb4 * 128] = int4{0, 0, 0, 0};
        }
    }
    __syncthreads();
    int4* dstg = (int4*)(rp + ((size_t)bs * CO + oc * 16) * 1024);
    const int4* srcs = (const int4*)spack;
    for (int i = tid; i < 2048; i += 256) dstg[i] = srcs[i];
}

// ---------------- K3: x-frags in registers, swapped GEMM1, b64 swizzled s_v, dbuf ----------------
// grid 1024 (b, tch of 16 t), 1024 threads (16 waves).
// Raw lgkmcnt-only barriers -> global prefetches stay in flight across stages.
__global__ __launch_bounds__(1024, 8) void k_main(const ushort* __restrict__ xg,
    const ushort* __restrict__ wvp, const ushort* __restrict__ rp,
    ushort* __restrict__ outw, float* __restrict__ stats) {
    int bid = blockIdx.x;
    int b = (bid & 7) + 8 * (bid >> 7);     // same-b blocks share an XCD
    int tch = (bid >> 3) & 15;
    int tid = threadIdx.x;
    int w = tid >> 6, lane = tid & 63, g4 = lane >> 4, l15 = lane & 15;

    __shared__ ushort s_v[2 * 32 * 16 * 32];   // dbuf [buf][o32][t16][k32] = 64 KB

    // ---- hoisted addresses ----
    int csw = ((l15 ^ w) & 7) << 2;
    int wbase = (l15 * 16 + w) * 32;
    int k0a = (g4 * 4) ^ csw;
    int k0b = (16 + g4 * 4) ^ csw;
    int ra[2][2];
#pragma unroll
    for (int oi = 0; oi < 2; ++oi) {
        int ol = w * 2 + oi;
        int cr = ((ol ^ l15) & 7) << 2;
        int hi = (g4 << 3) ^ (cr & 24);
        int lo0 = hi | (cr & 4);
        ra[oi][0] = (ol * 16 + l15) * 32 + lo0;
        ra[oi][1] = ra[oi][0] ^ 4;
    }

    // ---- x-fragments: loaded ONCE, live whole kernel (32 VGPR) ----
    bf16x8 xf0[4], xf1[4];
    {
        const ushort* xgb = xg + ((size_t)(b * 16) * 8192 + tch * 512 + w * 32 + l15) * 8;
#pragma unroll
        for (int ks = 0; ks < 4; ++ks) {
            xf0[ks] = *(const bf16x8*)&xgb[(size_t)(ks * 4 + g4) * 65536];
            xf1[ks] = *(const bf16x8*)&xgb[(size_t)(ks * 4 + g4) * 65536 + 128];
        }
    }

    // ---- stage-0 wv / rp fragments ----
    const ushort* wvl = wvp + lane * 8;
    const ushort* rpt = rp + ((size_t)(b * SS) * CO + w * 2) * 1024 + g4 * 128 + l15 * 8;
    bf16x8 wvf0[4], wvf1[4];
#pragma unroll
    for (int ks = 0; ks < 4; ++ks) {
        wvf0[ks] = *(const bf16x8*)&wvl[ks * 512];
        wvf1[ks] = *(const bf16x8*)&wvl[2048 + ks * 512];
    }
    bf16x8 r00 = *(const bf16x8*)&rpt[0];
    bf16x8 r01 = *(const bf16x8*)&rpt[512];
    bf16x8 r10 = *(const bf16x8*)&rpt[1024];
    bf16x8 r11 = *(const bf16x8*)&rpt[1536];

    f32x4 a00 = {0,0,0,0}, a01 = {0,0,0,0}, a10 = {0,0,0,0}, a11 = {0,0,0,0};

    auto pack4 = [&](f32x4 d, bool patch) -> uint2 {
        union { ushort us[4]; uint2 v; } p;
        p.us[0] = f2bf_fast(d[0]);
        p.us[1] = patch ? (ushort)0x3F80 : f2bf_fast(d[1]);
        p.us[2] = f2bf_fast(d[2]);
        p.us[3] = f2bf_fast(d[3]);
        return p.v;
    };
    auto gemm1 = [&](ushort* wbuf) {
        f32x4 d00 = {0,0,0,0}, d01 = {0,0,0,0}, d10 = {0,0,0,0}, d11 = {0,0,0,0};
        __builtin_amdgcn_s_setprio(1);
#pragma unroll
        for (int ks = 0; ks < 4; ++ks) {
            d00 = mfma16(xf0[ks], wvf0[ks], d00);
            d01 = mfma16(xf0[ks], wvf1[ks], d01);
            d10 = mfma16(xf1[ks], wvf0[ks], d10);
            d11 = mfma16(xf1[ks], wvf1[ks], d11);
        }
        __builtin_amdgcn_s_setprio(0);
        bool pt = (g4 == 2);           // k=25 slot -> 1.0 (bv trick)
        *(uint2*)&wbuf[wbase + k0a]        = pack4(d00, false);
        *(uint2*)&wbuf[wbase + 8192 + k0a] = pack4(d01, false);
        *(uint2*)&wbuf[wbase + k0b]        = pack4(d10, pt);
        *(uint2*)&wbuf[wbase + 8192 + k0b] = pack4(d11, pt);
    };

    gemm1(s_v);                        // stage 0 -> buf0

    int ss = 0, ob = 0;
    for (int st = 0; st < 12; ++st) {
        bar_lds();                     // buf(st&1) ready; vmcnt NOT drained
        int ss1 = (ss == 2) ? 0 : ss + 1;
        int ob1 = (ss == 2) ? ob + 1 : ob;
        bool more = (st < 11);

        // prefetch wv(st+1): consumed by GEMM1 at end of this iter
        if (more) {
            const ushort* wb = wvl + (ss1 * 4 + ob1) * 4096;
#pragma unroll
            for (int ks = 0; ks < 4; ++ks) {
                wvf0[ks] = *(const bf16x8*)&wb[ks * 512];
                wvf1[ks] = *(const bf16x8*)&wb[2048 + ks * 512];
            }
        }

        // ---- GEMM2(st): acc += v · relc^T ----
        {
            const ushort* rbuf = s_v + (st & 1) * 16384;
            union { uint2 q[2]; bf16x8 v; } av;
            av.q[0] = *(const uint2*)&rbuf[ra[0][0]];
            av.q[1] = *(const uint2*)&rbuf[ra[0][1]];
            __builtin_amdgcn_s_setprio(1);
            a00 = mfma16(av.v, r00, a00);
            a01 = mfma16(av.v, r01, a01);
            __builtin_amdgcn_s_setprio(0);
            av.q[0] = *(const uint2*)&rbuf[ra[1][0]];
            av.q[1] = *(const uint2*)&rbuf[ra[1][1]];
            __builtin_amdgcn_s_setprio(1);
            a10 = mfma16(av.v, r10, a10);
            a11 = mfma16(av.v, r11, a11);
            __builtin_amdgcn_s_setprio(0);
        }

        // prefetch rp(st+1): consumed by GEMM2 next iter (stays in flight across barrier)
        if (more) {
            const ushort* rb = rpt + ((size_t)ss1 * CO + ob1 * 32) * 1024;
            r00 = *(const bf16x8*)&rb[0];
            r01 = *(const bf16x8*)&rb[512];
            r10 = *(const bf16x8*)&rb[1024];
            r11 = *(const bf16x8*)&rb[1536];
        }

        // ---- epilogue at end of each ob ----
        if (ss == 2) {
            float ps = 0.f, pq = 0.f;
#pragma unroll
            for (int oi = 0; oi < 2; ++oi) {
                int o = ob * 32 + w * 2 + oi;
                size_t obase = (((size_t)b * CO + o) * TTOT + tch * 16 + g4 * 4) * VV;
#pragma unroll
                for (int ut = 0; ut < 2; ++ut) {
                    f32x4 av = (oi == 0) ? (ut == 0 ? a00 : a01) : (ut == 0 ? a10 : a11);
#pragma unroll
                    for (int r = 0; r < 4; ++r) {
                        float val = av[r];
                        ps += val; pq += val * val;     // u>=25 entries are exactly 0
                        if (ut == 0 || l15 < 9)
                            outw[obase + (size_t)r * VV + ut * 16 + l15] = f2bf_fast(val);
                    }
                }
            }
            a00 = f32x4{0,0,0,0}; a01 = f32x4{0,0,0,0};
            a10 = f32x4{0,0,0,0}; a11 = f32x4{0,0,0,0};
#pragma unroll
            for (int off = 32; off > 0; off >>= 1) {
                ps += __shfl_down(ps, off, 64);
                pq += __shfl_down(pq, off, 64);
            }
            if (lane == 0) {
                int g = ob * 8 + (w >> 1);
                atomicAdd(&stats[b * (GG * 2) + g * 2], ps);
                atomicAdd(&stats[b * (GG * 2) + g * 2 + 1], pq);
            }
        }

        // ---- GEMM1(st+1) -> other buffer ----
        if (more) gemm1(s_v + ((st + 1) & 1) * 16384);

        ss = ss1; ob = ob1;
    }
}

// ---------------- K4: GroupNorm apply + residual + ReLU ----------------
__global__ __launch_bounds__(256) void k_final(float* __restrict__ out,
    const ushort* __restrict__ outw, const float* __restrict__ x,
    const float* __restrict__ stats,
    const float* __restrict__ gw, const float* __restrict__ gb) {
    size_t i = ((size_t)blockIdx.x * 256 + threadIdx.x) * 4;
    int o = (int)((i / (TTOT * VV)) % CO);
    int b = (int)(i / ((size_t)CO * TTOT * VV));
    int gg = o >> 2;
    float s0 = stats[b * (GG * 2) + gg * 2];
    float s1 = stats[b * (GG * 2) + gg * 2 + 1];
    const float inv = 1.0f / (4 * TTOT * VV);
    float mu = s0 * inv;
    float var = s1 * inv - mu * mu;
    float rs = rsqrtf(var + EPSV) * gw[o];
    float sh = gb[o] - mu * rs;

    ushort4 rw = *(const ushort4*)(outw + i);
    float4 xr = *(const float4*)(x + i);
    float4 res;
    res.x = fmaxf(bf2f(rw.x) * rs + sh + xr.x, 0.f);
    res.y = fmaxf(bf2f(rw.y) * rs + sh + xr.y, 0.f);
    res.z = fmaxf(bf2f(rw.z) * rs + sh + xr.z, 0.f);
    res.w = fmaxf(bf2f(rw.w) * rs + sh + xr.w, 0.f);
    *(float4*)(out + i) = res;
}

extern "C" void kernel_launch(void* const* d_in, const int* in_sizes, int n_in,
                              void* d_out, int out_size, void* d_ws, size_t ws_size,
                              hipStream_t stream) {
    const float* x     = (const float*)d_in[0];
    const float* Wq    = (const float*)d_in[1];
    const float* bq    = (const float*)d_in[2];
    const float* Wk    = (const float*)d_in[3];
    const float* bk    = (const float*)d_in[4];
    const float* Wv    = (const float*)d_in[5];
    const float* bv    = (const float*)d_in[6];
    const float* Wr    = (const float*)d_in[7];
    const float* br    = (const float*)d_in[8];
    const float* A     = (const float*)d_in[9];
    const float* alpha = (const float*)d_in[10];
    const float* gw    = (const float*)d_in[11];
    const float* gb    = (const float*)d_in[12];
    float* out = (float*)d_out;

    float*  xm    = (float*)d_ws;                               // 204800 f
    float*  stats = xm + (size_t)BB * CC * VV;                  // 4096 f
    ushort* wvp   = (ushort*)(stats + (size_t)BB * GG * 2);     // 49152 us
    ushort* rp    = wvp + 49152;                                // 25,165,824 us
    ushort* outw  = rp + (size_t)BB * SS * CO * 1024;           // 52,428,800 us
    ushort* xg    = outw + (size_t)BB * CO * TTOT * VV;         // 67,108,864 us
    // q/k overlay in outw region (consumed before k_main writes outw)
    float*  qb    = (float*)outw;
    float*  kbuf  = qb + (size_t)BB * SS * RR * VV;

    hipMemsetAsync(stats, 0, (size_t)BB * GG * 2 * sizeof(float), stream);
    k_xpose<<<BB * 16, 512, 0, stream>>>(x, xg, xm);
    k_pack_wv<<<12, 512, 0, stream>>>(Wv, wvp);
    k_qk<<<BB * SS, 512, 0, stream>>>(xm, Wq, bq, Wk, bk, qb, kbuf);
    k_relcpack<<<BB * SS * 8, 256, 0, stream>>>(qb, kbuf, Wr, br, A, alpha, bv, rp);
    k_main<<<1024, 1024, 0, stream>>>(xg, wvp, rp, outw, stats);
    k_final<<<(BB * CO * TTOT * VV) / (256 * 4), 256, 0, stream>>>(out, outw, x, stats, gw, gb);
}

// Round 9
// 428.171 us; speedup vs baseline: 2.4202x; 2.4202x over previous
//
#include <hip/hip_runtime.h>

#define BB 64
#define CC 128
#define CO 128
#define TTOT 256
#define VV 25
#define SS 3
#define RR 16
#define GG 32
#define EPSV 1e-5f

typedef __attribute__((ext_vector_type(8))) __bf16 bf16x8;
typedef __attribute__((ext_vector_type(4))) float f32x4;

static __device__ __forceinline__ ushort f2bf(float f) {      // RNE
    unsigned u = __float_as_uint(f);
    u = (u + 0x7FFF + ((u >> 16) & 1)) >> 16;
    return (ushort)u;
}
static __device__ __forceinline__ ushort f2bf_fast(float f) { // round-half-up
    return (ushort)((__float_as_uint(f) + 0x8000u) >> 16);
}
static __device__ __forceinline__ float bf2f(ushort h) {
    return __uint_as_float(((unsigned)h) << 16);
}
static __device__ __forceinline__ f32x4 mfma16(bf16x8 a, bf16x8 b, f32x4 c) {
    return __builtin_amdgcn_mfma_f32_16x16x32_bf16(a, b, c, 0, 0, 0);
}
// raw barrier: LDS-visibility only; global prefetches stay in flight (m201 pattern)
static __device__ __forceinline__ void bar_lds() {
    asm volatile("s_waitcnt lgkmcnt(0)" ::: "memory");
    __builtin_amdgcn_s_barrier();
}

// ---------------- K0: x -> xg (bf16 frag layout, k padded to 32 w/ zeros) + xm ----------------
// xg: [b][c8(16)][n' = t*32+k (8192)][cc(8)] bf16
__global__ __launch_bounds__(512) void k_xpose(const float* __restrict__ x,
                                               ushort* __restrict__ xg,
                                               float* __restrict__ xm) {
    int bid = blockIdx.x;                  // b*16 + c8
    int b = bid >> 4, c8 = bid & 15;
    int tid = threadIdx.x;
    __shared__ float sx[8 * 800];
    float xsum = 0.f;
    const float* xb = x + ((size_t)b * CC + c8 * 8) * (TTOT * VV);
    ushort* xo = xg + (size_t)bid * 8192 * 8;
    int cc = tid / VV, vv = tid % VV;      // for tid<200
    for (int ti = 0; ti < 8; ++ti) {       // t-chunks of 32
        for (int i = tid; i < 1600; i += 512) {
            int c = i / 200, q = i % 200;
            *(float4*)&sx[c * 800 + q * 4] =
                *(const float4*)&xb[(size_t)c * (TTOT * VV) + ti * 800 + q * 4];
        }
        __syncthreads();
        for (int i = tid; i < 1024; i += 512) {
            int t = i >> 5, k = i & 31;
            union { ushort us[8]; int4 v4; } u;
            if (k < VV) {
#pragma unroll
                for (int c = 0; c < 8; ++c) u.us[c] = f2bf(sx[c * 800 + t * VV + k]);
            } else u.v4 = int4{0, 0, 0, 0};
            *(int4*)&xo[(size_t)((ti * 32 + t) * 32 + k) * 8] = u.v4;
        }
        if (tid < 200) {
#pragma unroll
            for (int t = 0; t < 32; ++t) xsum += sx[cc * 800 + t * VV + vv];
        }
        __syncthreads();
    }
    if (tid < 200) xm[((size_t)b * CC + c8 * 8 + cc) * VV + vv] = xsum * (1.0f / TTOT);
}

// ---------------- K1b: pack Wv into bf16 MFMA fragment order ----------------
__global__ __launch_bounds__(512) void k_pack_wv(const float* __restrict__ Wv,
                                                 ushort* __restrict__ wvp) {
    int t = blockIdx.x * 512 + threadIdx.x;      // < 6144
    int lane = t & 63;
    int ks = (t >> 6) & 3;
    int mt = (t >> 8) & 1;
    int ob = (t >> 9) & 3;
    int s  = t >> 11;
    int o  = ob * 32 + mt * 16 + (lane & 15);
    int c0 = (ks * 4 + (lane >> 4)) * 8;
    const float* src = Wv + ((size_t)s * CO + o) * CC + c0;
    float4 a = *(const float4*)src;
    float4 b = *(const float4*)(src + 4);
    union { ushort us[8]; int4 v; } u;
    u.us[0] = f2bf(a.x); u.us[1] = f2bf(a.y); u.us[2] = f2bf(a.z); u.us[3] = f2bf(a.w);
    u.us[4] = f2bf(b.x); u.us[5] = f2bf(b.y); u.us[6] = f2bf(b.z); u.us[7] = f2bf(b.w);
    *(int4*)&wvp[(size_t)t * 8] = u.v;
}

// ---------------- K2a: q,k projections ----------------
__global__ __launch_bounds__(512) void k_qk(const float* __restrict__ xm,
    const float* __restrict__ Wq, const float* __restrict__ bq,
    const float* __restrict__ Wk, const float* __restrict__ bk,
    float* __restrict__ qb, float* __restrict__ kbuf) {
    int bs = blockIdx.x;
    int b = bs / SS, s = bs % SS;
    int tid = threadIdx.x;
    __shared__ float sxm[CC * VV];
    for (int i = tid; i < CC * VV; i += 512) sxm[i] = xm[(size_t)b * CC * VV + i];
    __syncthreads();
    if (tid < RR * VV) {
        int r = tid / VV, u = tid % VV;
        const float* wq = Wq + ((size_t)s * RR + r) * CC;
        const float* wk = Wk + ((size_t)s * RR + r) * CC;
        float aq = bq[s * RR + r], ak = bk[s * RR + r];
        for (int c = 0; c < CC; ++c) { float xv = sxm[c * VV + u]; aq += wq[c] * xv; ak += wk[c] * xv; }
        qb[bs * 400 + tid] = aq;
        kbuf[bs * 400 + tid] = ak;
    }
}

// ---------------- K2b: relc -> packed bf16 B-fragments; slot k=25 carries bv*rowsum ----------------
__global__ __launch_bounds__(256) void k_relcpack(const float* __restrict__ qb,
    const float* __restrict__ kbuf, const float* __restrict__ Wr,
    const float* __restrict__ br, const float* __restrict__ A,
    const float* __restrict__ alpha, const float* __restrict__ bv,
    ushort* __restrict__ rp) {
    int blk = blockIdx.x;
    int oc = blk & 7, bs = blk >> 3;
    int s = bs % SS;
    int tid = threadIdx.x;
    __shared__ float sq[RR * VV], sk[RR * VV];
    __shared__ float srel[RR][VV * VV];
    __shared__ ushort spack[16 * 1024];
    for (int i = tid; i < RR * VV; i += 256) { sq[i] = qb[bs * 400 + i]; sk[i] = kbuf[bs * 400 + i]; }
    __syncthreads();
    for (int i = tid; i < RR * VV * VV; i += 256) {
        int r = i / (VV * VV), uv = i % (VV * VV);
        srel[r][uv] = tanhf(sq[r * VV + uv / VV] - sk[r * VV + uv % VV]);
    }
    __syncthreads();
    float al = alpha[0];
    for (int i = tid; i < 512; i += 256) {
        int ol = i >> 5, u = i & 31;
        int o = oc * 16 + ol;
        ushort* dst = &spack[ol * 1024 + (u >> 4) * 512 + (u & 15) * 8];
        if (u < VV) {
            float acc[VV];
            float base = br[s * CO + o];
#pragma unroll
            for (int k = 0; k < VV; ++k) acc[k] = base;
            const float* wr = Wr + ((size_t)s * CO + o) * RR;
#pragma unroll
            for (int r = 0; r < RR; ++r) {
                float w = wr[r];
                const float* sr = &srel[r][u * VV];
#pragma unroll
                for (int k = 0; k < VV; ++k) acc[k] += w * sr[k];
            }
            const float* Ab = A + (size_t)s * VV * VV + u * VV;
            float vals[VV]; float rsum = 0.f;
#pragma unroll
            for (int k = 0; k < VV; ++k) { vals[k] = acc[k] * al + Ab[k]; rsum += vals[k]; }
            float bvt = bv[s * CO + o] * rsum;     // pairs with s_v slot k=25 == 1.0
#pragma unroll
            for (int kb4 = 0; kb4 < 4; ++kb4) {
                union { ushort us[8]; int4 v; } pk;
#pragma unroll
                for (int j = 0; j < 8; ++j) {
                    int kk = kb4 * 8 + j;
                    pk.us[j] = (kk < VV) ? f2bf(vals[kk])
                             : (kk == VV) ? f2bf(bvt) : (ushort)0;
                }
                *(int4*)&dst[kb4 * 128] = pk.v;
            }
        } else {
#pragma unroll
            for (int kb4 = 0; kb4 < 4; ++kb4)
                *(int4*)&dst[kb4 * 128] = int4{0, 0, 0, 0};
        }
    }
    __syncthreads();
    int4* dstg = (int4*)(rp + ((size_t)bs * CO + oc * 16) * 1024);
    const int4* srcs = (const int4*)spack;
    for (int i = tid; i < 2048; i += 256) dstg[i] = srcs[i];
}

// ---------------- K3: x-frags in registers, swapped GEMM1, b64 swizzled s_v, dbuf ----------------
// grid 1024 (b, tch of 16 t), 1024 threads (16 waves).
// Raw lgkmcnt-only barriers -> global prefetches stay in flight across stages.
__global__ __launch_bounds__(1024, 4) void k_main(const ushort* __restrict__ xg,
    const ushort* __restrict__ wvp, const ushort* __restrict__ rp,
    ushort* __restrict__ outw, float* __restrict__ stats) {
    int bid = blockIdx.x;
    int b = (bid & 7) + 8 * (bid >> 7);     // same-b blocks share an XCD
    int tch = (bid >> 3) & 15;
    int tid = threadIdx.x;
    int w = tid >> 6, lane = tid & 63, g4 = lane >> 4, l15 = lane & 15;

    __shared__ ushort s_v[2 * 32 * 16 * 32];   // dbuf [buf][o32][t16][k32] = 64 KB

    // ---- hoisted addresses ----
    int csw = ((l15 ^ w) & 7) << 2;
    int wbase = (l15 * 16 + w) * 32;
    int k0a = (g4 * 4) ^ csw;
    int k0b = (16 + g4 * 4) ^ csw;
    int ra[2][2];
#pragma unroll
    for (int oi = 0; oi < 2; ++oi) {
        int ol = w * 2 + oi;
        int cr = ((ol ^ l15) & 7) << 2;
        int hi = (g4 << 3) ^ (cr & 24);
        int lo0 = hi | (cr & 4);
        ra[oi][0] = (ol * 16 + l15) * 32 + lo0;
        ra[oi][1] = ra[oi][0] ^ 4;
    }

    // ---- x-fragments: loaded ONCE, live whole kernel (32 VGPR) ----
    bf16x8 xf0[4], xf1[4];
    {
        const ushort* xgb = xg + ((size_t)(b * 16) * 8192 + tch * 512 + w * 32 + l15) * 8;
#pragma unroll
        for (int ks = 0; ks < 4; ++ks) {
            xf0[ks] = *(const bf16x8*)&xgb[(size_t)(ks * 4 + g4) * 65536];
            xf1[ks] = *(const bf16x8*)&xgb[(size_t)(ks * 4 + g4) * 65536 + 128];
        }
    }

    // ---- stage-0 wv / rp fragments ----
    const ushort* wvl = wvp + lane * 8;
    const ushort* rpt = rp + ((size_t)(b * SS) * CO + w * 2) * 1024 + g4 * 128 + l15 * 8;
    bf16x8 wvf0[4], wvf1[4];
#pragma unroll
    for (int ks = 0; ks < 4; ++ks) {
        wvf0[ks] = *(const bf16x8*)&wvl[ks * 512];
        wvf1[ks] = *(const bf16x8*)&wvl[2048 + ks * 512];
    }
    bf16x8 r00 = *(const bf16x8*)&rpt[0];
    bf16x8 r01 = *(const bf16x8*)&rpt[512];
    bf16x8 r10 = *(const bf16x8*)&rpt[1024];
    bf16x8 r11 = *(const bf16x8*)&rpt[1536];

    f32x4 a00 = {0,0,0,0}, a01 = {0,0,0,0}, a10 = {0,0,0,0}, a11 = {0,0,0,0};

    auto pack4 = [&](f32x4 d, bool patch) -> uint2 {
        union { ushort us[4]; uint2 v; } p;
        p.us[0] = f2bf_fast(d[0]);
        p.us[1] = patch ? (ushort)0x3F80 : f2bf_fast(d[1]);
        p.us[2] = f2bf_fast(d[2]);
        p.us[3] = f2bf_fast(d[3]);
        return p.v;
    };
    auto gemm1 = [&](ushort* wbuf) {
        f32x4 d00 = {0,0,0,0}, d01 = {0,0,0,0}, d10 = {0,0,0,0}, d11 = {0,0,0,0};
        __builtin_amdgcn_s_setprio(1);
#pragma unroll
        for (int ks = 0; ks < 4; ++ks) {
            d00 = mfma16(xf0[ks], wvf0[ks], d00);
            d01 = mfma16(xf0[ks], wvf1[ks], d01);
            d10 = mfma16(xf1[ks], wvf0[ks], d10);
            d11 = mfma16(xf1[ks], wvf1[ks], d11);
        }
        __builtin_amdgcn_s_setprio(0);
        bool pt = (g4 == 2);           // k=25 slot -> 1.0 (bv trick)
        *(uint2*)&wbuf[wbase + k0a]        = pack4(d00, false);
        *(uint2*)&wbuf[wbase + 8192 + k0a] = pack4(d01, false);
        *(uint2*)&wbuf[wbase + k0b]        = pack4(d10, pt);
        *(uint2*)&wbuf[wbase + 8192 + k0b] = pack4(d11, pt);
    };

    gemm1(s_v);                        // stage 0 -> buf0

    int ss = 0, ob = 0;
    for (int st = 0; st < 12; ++st) {
        bar_lds();                     // buf(st&1) ready; vmcnt NOT drained
        int ss1 = (ss == 2) ? 0 : ss + 1;
        int ob1 = (ss == 2) ? ob + 1 : ob;
        bool more = (st < 11);

        // prefetch wv(st+1): consumed by GEMM1 at end of this iter
        if (more) {
            const ushort* wb = wvl + (ss1 * 4 + ob1) * 4096;
#pragma unroll
            for (int ks = 0; ks < 4; ++ks) {
                wvf0[ks] = *(const bf16x8*)&wb[ks * 512];
                wvf1[ks] = *(const bf16x8*)&wb[2048 + ks * 512];
            }
        }

        // ---- GEMM2(st): acc += v · relc^T ----
        {
            const ushort* rbuf = s_v + (st & 1) * 16384;
            union { uint2 q[2]; bf16x8 v; } av;
            av.q[0] = *(const uint2*)&rbuf[ra[0][0]];
            av.q[1] = *(const uint2*)&rbuf[ra[0][1]];
            __builtin_amdgcn_s_setprio(1);
            a00 = mfma16(av.v, r00, a00);
            a01 = mfma16(av.v, r01, a01);
            __builtin_amdgcn_s_setprio(0);
            av.q[0] = *(const uint2*)&rbuf[ra[1][0]];
            av.q[1] = *(const uint2*)&rbuf[ra[1][1]];
            __builtin_amdgcn_s_setprio(1);
            a10 = mfma16(av.v, r10, a10);
            a11 = mfma16(av.v, r11, a11);
            __builtin_amdgcn_s_setprio(0);
        }

        // prefetch rp(st+1): consumed by GEMM2 next iter (stays in flight across barrier)
        if (more) {
            const ushort* rb = rpt + ((size_t)ss1 * CO + ob1 * 32) * 1024;
            r00 = *(const bf16x8*)&rb[0];
            r01 = *(const bf16x8*)&rb[512];
            r10 = *(const bf16x8*)&rb[1024];
            r11 = *(const bf16x8*)&rb[1536];
        }

        // ---- epilogue at end of each ob ----
        if (ss == 2) {
            float ps = 0.f, pq = 0.f;
#pragma unroll
            for (int oi = 0; oi < 2; ++oi) {
                int o = ob * 32 + w * 2 + oi;
                size_t obase = (((size_t)b * CO + o) * TTOT + tch * 16 + g4 * 4) * VV;
#pragma unroll
                for (int ut = 0; ut < 2; ++ut) {
                    f32x4 av = (oi == 0) ? (ut == 0 ? a00 : a01) : (ut == 0 ? a10 : a11);
#pragma unroll
                    for (int r = 0; r < 4; ++r) {
                        float val = av[r];
                        ps += val; pq += val * val;     // u>=25 entries are exactly 0
                        if (ut == 0 || l15 < 9)
                            outw[obase + (size_t)r * VV + ut * 16 + l15] = f2bf_fast(val);
                    }
                }
            }
            a00 = f32x4{0,0,0,0}; a01 = f32x4{0,0,0,0};
            a10 = f32x4{0,0,0,0}; a11 = f32x4{0,0,0,0};
#pragma unroll
            for (int off = 32; off > 0; off >>= 1) {
                ps += __shfl_down(ps, off, 64);
                pq += __shfl_down(pq, off, 64);
            }
            if (lane == 0) {
                int g = ob * 8 + (w >> 1);
                atomicAdd(&stats[b * (GG * 2) + g * 2], ps);
                atomicAdd(&stats[b * (GG * 2) + g * 2 + 1], pq);
            }
        }

        // ---- GEMM1(st+1) -> other buffer ----
        if (more) gemm1(s_v + ((st + 1) & 1) * 16384);

        ss = ss1; ob = ob1;
    }
}

// ---------------- K4: GroupNorm apply + residual + ReLU ----------------
__global__ __launch_bounds__(256) void k_final(float* __restrict__ out,
    const ushort* __restrict__ outw, const float* __restrict__ x,
    const float* __restrict__ stats,
    const float* __restrict__ gw, const float* __restrict__ gb) {
    size_t i = ((size_t)blockIdx.x * 256 + threadIdx.x) * 4;
    int o = (int)((i / (TTOT * VV)) % CO);
    int b = (int)(i / ((size_t)CO * TTOT * VV));
    int gg = o >> 2;
    float s0 = stats[b * (GG * 2) + gg * 2];
    float s1 = stats[b * (GG * 2) + gg * 2 + 1];
    const float inv = 1.0f / (4 * TTOT * VV);
    float mu = s0 * inv;
    float var = s1 * inv - mu * mu;
    float rs = rsqrtf(var + EPSV) * gw[o];
    float sh = gb[o] - mu * rs;

    ushort4 rw = *(const ushort4*)(outw + i);
    float4 xr = *(const float4*)(x + i);
    float4 res;
    res.x = fmaxf(bf2f(rw.x) * rs + sh + xr.x, 0.f);
    res.y = fmaxf(bf2f(rw.y) * rs + sh + xr.y, 0.f);
    res.z = fmaxf(bf2f(rw.z) * rs + sh + xr.z, 0.f);
    res.w = fmaxf(bf2f(rw.w) * rs + sh + xr.w, 0.f);
    *(float4*)(out + i) = res;
}

extern "C" void kernel_launch(void* const* d_in, const int* in_sizes, int n_in,
                              void* d_out, int out_size, void* d_ws, size_t ws_size,
                              hipStream_t stream) {
    const float* x     = (const float*)d_in[0];
    const float* Wq    = (const float*)d_in[1];
    const float* bq    = (const float*)d_in[2];
    const float* Wk    = (const float*)d_in[3];
    const float* bk    = (const float*)d_in[4];
    const float* Wv    = (const float*)d_in[5];
    const float* bv    = (const float*)d_in[6];
    const float* Wr    = (const float*)d_in[7];
    const float* br    = (const float*)d_in[8];
    const float* A     = (const float*)d_in[9];
    const float* alpha = (const float*)d_in[10];
    const float* gw    = (const float*)d_in[11];
    const float* gb    = (const float*)d_in[12];
    float* out = (float*)d_out;

    float*  xm    = (float*)d_ws;                               // 204800 f
    float*  stats = xm + (size_t)BB * CC * VV;                  // 4096 f
    ushort* wvp   = (ushort*)(stats + (size_t)BB * GG * 2);     // 49152 us
    ushort* rp    = wvp + 49152;                                // 25,165,824 us
    ushort* outw  = rp + (size_t)BB * SS * CO * 1024;           // 52,428,800 us
    ushort* xg    = outw + (size_t)BB * CO * TTOT * VV;         // 67,108,864 us
    // q/k overlay in outw region (consumed before k_main writes outw)
    float*  qb    = (float*)outw;
    float*  kbuf  = qb + (size_t)BB * SS * RR * VV;

    hipMemsetAsync(stats, 0, (size_t)BB * GG * 2 * sizeof(float), stream);
    k_xpose<<<BB * 16, 512, 0, stream>>>(x, xg, xm);
    k_pack_wv<<<12, 512, 0, stream>>>(Wv, wvp);
    k_qk<<<BB * SS, 512, 0, stream>>>(xm, Wq, bq, Wk, bk, qb, kbuf);
    k_relcpack<<<BB * SS * 8, 256, 0, stream>>>(qb, kbuf, Wr, br, A, alpha, bv, rp);
    k_main<<<1024, 1024, 0, stream>>>(xg, wvp, rp, outw, stats);
    k_final<<<(BB * CO * TTOT * VV) / (256 * 4), 256, 0, stream>>>(out, outw, x, stats, gw, gb);
}